// Round 2
// baseline (143.014 us; speedup 1.0000x reference)
//
#include <hip/hip_runtime.h>
#include <math.h>

#define PH 7
#define PW 7
#define FH 16
#define FW 16
#define FC 512
#define NROI 64
#define NIMG 16   // B*N = 4*4

// One block per (img, roi, ph-row). 128 threads, each owns a float4 of channels.
// Each block reads its row strip once and produces all 7 pw bins of the row.
__global__ __launch_bounds__(128) void ROIPooling_73598559584965_kernel(
    const float* __restrict__ fm,    // (NIMG, FH, FW, FC)
    const float* __restrict__ rois,  // (NIMG, NROI, 4)
    float* __restrict__ out)         // (NIMG, NROI, PH, PW, FC)
{
    int bid = blockIdx.x;
    int ph  = bid % PH;
    int ir  = bid / PH;              // img*NROI + roi
    int img = ir / NROI;

    const float* r = rois + (size_t)ir * 4;
    float r0 = r[0], r1 = r[1], r2 = r[2], r3 = r[3];
    int h0 = (int)(FH * r0);
    int w0 = (int)(FW * r1);
    int h1 = (int)(FH * r2);
    int w1 = (int)(FW * r3);
    int hs = (h1 - h0) / PH;   // positive region in test; trunc == floor here
    int ws = (w1 - w0) / PW;

    int hb0, hb1;
    if (hs > 0) {
        hb0 = h0 + ph * hs;
        hb1 = (ph == PH - 1) ? h1 : (h0 + (ph + 1) * hs);
    } else {
        hb0 = (ph == PH - 1) ? h0 : 0;
        hb1 = (ph == PH - 1) ? h1 : 0;
    }
    hb0 = max(max(hb0, 0), h0);
    hb1 = min(min(hb1, FH), h1);

    // w bin boundaries: bin pw spans [w0+pw*ws, w0+(pw+1)*ws), last bin to w1
    int wb[PW + 1];
    if (ws > 0) {
        #pragma unroll
        for (int pw = 0; pw < PW; ++pw) wb[pw] = w0 + pw * ws;
        wb[PW] = w1;
        wb[PW - 1] = min(wb[PW - 1], w1);   // safety
        #pragma unroll
        for (int pw = 0; pw <= PW; ++pw) wb[pw] = min(max(wb[pw], max(w0, 0)), min(w1, FW));
    } else {
        // all in-ROI pixels fall into the last bin
        #pragma unroll
        for (int pw = 0; pw < PW; ++pw) wb[pw] = max(w0, 0);
        wb[PW] = min(w1, FW);
        #pragma unroll
        for (int pw = 0; pw < PW; ++pw) wb[pw] = (pw == PW - 1) ? wb[pw] : wb[PW]; // bins 0..5 empty
        // make bins 0..5 empty: set their start == end
        #pragma unroll
        for (int pw = 0; pw < PW - 1; ++pw) wb[pw] = wb[PW];
        wb[PW - 1] = max(w0, 0);
        // note: wb[6]=w0, wb[7]=w1 -> only last bin non-empty; bins 0..5 have
        // start=wb[pw]=w1,end(next)=... handled below via per-bin (lo,hi)
    }

    int c4 = threadIdx.x;  // 0..127 -> float4 channel group
    const float4* fmv = (const float4*)fm;

    float4 acc[PW];
    #pragma unroll
    for (int pw = 0; pw < PW; ++pw) {
        acc[pw].x = -INFINITY; acc[pw].y = -INFINITY;
        acc[pw].z = -INFINITY; acc[pw].w = -INFINITY;
    }

    for (int h = hb0; h < hb1; ++h) {
        size_t rowbase = ((size_t)(img * FH + h) * FW) * (FC / 4);
        #pragma unroll
        for (int pw = 0; pw < PW; ++pw) {
            int lo = wb[pw];
            int hi = (ws > 0) ? wb[pw + 1] : ((pw == PW - 1) ? wb[PW] : lo);
            for (int w = lo; w < hi; ++w) {
                float4 v = fmv[rowbase + (size_t)w * (FC / 4) + c4];
                acc[pw].x = fmaxf(acc[pw].x, v.x);
                acc[pw].y = fmaxf(acc[pw].y, v.y);
                acc[pw].z = fmaxf(acc[pw].z, v.z);
                acc[pw].w = fmaxf(acc[pw].w, v.w);
            }
        }
    }

    size_t obase = ((size_t)(ir * PH + ph) * PW) * (FC / 4) + c4;
    #pragma unroll
    for (int pw = 0; pw < PW; ++pw) {
        ((float4*)out)[obase + (size_t)pw * (FC / 4)] = acc[pw];
    }
}

extern "C" void kernel_launch(void* const* d_in, const int* in_sizes, int n_in,
                              void* d_out, int out_size, void* d_ws, size_t ws_size,
                              hipStream_t stream) {
    const float* fm   = (const float*)d_in[0];
    const float* rois = (const float*)d_in[1];
    float* out = (float*)d_out;

    int nblocks = NIMG * NROI * PH;  // 7168
    ROIPooling_73598559584965_kernel<<<nblocks, 128, 0, stream>>>(fm, rois, out);
}